// Round 8
// baseline (87.916 us; speedup 1.0000x reference)
//
#include <hip/hip_runtime.h>

// RNNT (Transducer) alpha-recursion loss, forward, mean reduction.
// B=4, T=512, U=100 (U+1=101 cols), V=1024, fp32.
//
// R8: ONE kernel, producer/consumer OVERLAP via per-window flags.
//   alpha[t][u] = alpha[t-1][u]*fB + alpha[t][u-1]*fE (linear domain),
//   fB/fE = exp2(log2e*logit) as f32 factors; f64 DP state (f32 overflowed:
//   answer ~ -700 log2); wave-uniform ldexp rescale every W=16 steps.
//
//   Blocks 0..3: DP consumers, one wave each; lane l owns columns u=2l,2l+1;
//     left neighbor via DPP wave_shr:1 on both 32b halves of the double.
//     Modulo-3 pipeline of 16-row float4 groups; before loading window k the
//     wave acquire-spins on g_done[b][k] (signaled count == rows in window).
//   Blocks 4..615: producers; block 4 + pid covers rows r=4*(pid>>2)..+3 of
//     batch pid&3 (low diagonals dispatched first -> DP starts ~immediately).
//     Each wave gathers one anti-diagonal row (rect-masked scattered loads
//     from the 847MB logits), stores float4 factors to g_PK, then lane 0
//     atomicAdd-releases g_done[b][r>>4]. Producers never wait -> no deadlock;
//     spinning consumers hold only 4 CUs.
//   Last DP finisher reduces g_ps -> out and resets g_done/g_ctr in-launch
//   (graph-replay deterministic; g_done is zero-init at module load).

constexpr int B = 4, T = 512, U = 100, Up1 = 101, V = 1024;
constexpr int DIAGS = T + U;        // 612
constexpr int W = 16;               // DP steps / rows per window
constexpr int NWIN = (DIAGS + W - 1) / W;   // 39 windows
constexpr float LOG2E = 1.44269504088896340736f;
constexpr float LN2 = 0.69314718055994530942f;

__device__ float4 g_PK[(size_t)B * DIAGS * 64];
__device__ int g_done[B][NWIN];     // zero-init at load; reset by finisher
__device__ float g_ps[B];           // per-sample log2(alpha_final)
__device__ int g_ctr = 0;

__device__ __forceinline__ int clampi(int x, int lo, int hi) {
  return x < lo ? lo : (x > hi ? hi : x);
}
__device__ __forceinline__ float fexp2(float x) {
  float r; asm("v_exp_f32 %0, %1" : "=v"(r) : "v"(x)); return r;
}
__device__ __forceinline__ float flog2(float x) {
  float r; asm("v_log_f32 %0, %1" : "=v"(r) : "v"(x)); return r;
}
// whole-wave shift by 1 on a double: lane l receives lane l-1's value
// (lane 0 keeps its own; its left factor is 0 so it never contributes)
__device__ __forceinline__ double wave_shr1_f64(double x) {
  int hi = __double2hiint(x), lo = __double2loint(x);
  hi = __builtin_amdgcn_update_dpp(hi, hi, 0x138 /*WF_SR1*/, 0xF, 0xF, false);
  lo = __builtin_amdgcn_update_dpp(lo, lo, 0x138 /*WF_SR1*/, 0xF, 0xF, false);
  return __hiloint2double(hi, lo);
}

__global__ __launch_bounds__(256, 1)
void rnnt_fused(const float* __restrict__ logits,
                const int* __restrict__ labels,
                const int* __restrict__ logit_len,
                const int* __restrict__ label_len,
                float* __restrict__ out) {
  const int lane = threadIdx.x & 63;

  // ================= producers =================
  if (blockIdx.x >= B) {
    const int pid = blockIdx.x - B;        // 0..611
    const int b = pid & 3;
    const int r = (pid >> 2) * 4 + (threadIdx.x >> 6);   // anti-diagonal row
    const int Tb = clampi(logit_len[b], 1, T);
    const int Ub = clampi(label_len[b], 1, U);

    if (r <= Tb - 1 + Ub) {                // rows past answer diag: skip stores
      const float* lg = logits + (size_t)b * T * Up1 * V;
      const int u0 = 2 * lane, u1 = u0 + 1;
      float4 v; v.x = v.y = v.z = v.w = 0.0f;   // 0 == linear -inf

      int tx = r - u0;                     // blank[tx][u0]
      if (u0 <= Ub && tx >= 0 && tx <= Tb - 1)
        v.x = fexp2(LOG2E * lg[((size_t)tx * Up1 + u0) * V]);
      int ty = r - u1;                     // blank[ty][u1]
      if (u1 <= Ub && ty >= 0 && ty <= Tb - 1)
        v.y = fexp2(LOG2E * lg[((size_t)ty * Up1 + u1) * V]);
      int tz = r - u0 + 1;                 // emit[tz][u0-1]
      if (u0 >= 1 && u0 <= Ub && tz >= 0 && tz <= Tb - 1) {
        int lab = clampi(labels[b * U + (u0 - 1)], 0, V - 1);
        v.z = fexp2(LOG2E * lg[((size_t)tz * Up1 + (u0 - 1)) * V + lab]);
      }
      int tw = r - u0;                     // emit[tw][u0]
      if (u0 <= Ub - 1 && tw >= 0 && tw <= Tb - 1) {
        int lab = clampi(labels[b * U + u0], 0, V - 1);
        v.w = fexp2(LOG2E * lg[((size_t)tw * Up1 + u0) * V + lab]);
      }
      g_PK[((size_t)b * DIAGS + r) * 64 + lane] = v;
    }
    // signal row done (release orders the stores above before the count)
    if (lane == 0)
      __hip_atomic_fetch_add(&g_done[b][r >> 4], 1, __ATOMIC_RELEASE,
                             __HIP_MEMORY_SCOPE_AGENT);
    return;
  }

  // ================= consumers (blocks 0..3, wave 0) =================
  if (threadIdx.x >= 64) return;
  const int b = blockIdx.x;
  const int Tb = clampi(logit_len[b], 1, T);
  const int Ub = clampi(label_len[b], 1, U);
  const int smax = Tb - 1 + Ub;            // diagonal (= step) of answer cell
  const float4* PK = g_PK + (size_t)b * DIAGS * 64;

  double A = (lane == 0) ? 1.0 : 0.0;      // alpha[0][0] = 1 (diag 0 done)
  double Bc = 0.0;
  int scale = 0;                           // accumulated log2 rescale

  float4 ba[W], bb[W], bc[W];

  // wait until all rows of window grp are signaled (acquire pairs with the
  // producers' release adds; whole wave spins on the same address)
#define WAITW(grp)                                                             \
  {                                                                            \
    int need_ = ((grp) * W + W <= DIAGS) ? W : (DIAGS - (grp) * W);            \
    while (__hip_atomic_load(&g_done[b][grp], __ATOMIC_ACQUIRE,                \
                             __HIP_MEMORY_SCOPE_AGENT) < need_)                \
      __builtin_amdgcn_s_sleep(1);                                             \
  }

  // group g holds rows g*W .. g*W+W-1 (step s consumes row s-1)
#define LOADG(buf, grp)                                                        \
  {                                                                            \
    int base_ = (grp) * W;                                                     \
    _Pragma("unroll")                                                          \
    for (int j_ = 0; j_ < W; ++j_) {                                           \
      int r_ = base_ + j_; if (r_ > DIAGS - 1) r_ = DIAGS - 1;                 \
      buf[j_] = PK[(size_t)r_ * 64 + lane];                                    \
    }                                                                          \
  }

  // window grp = steps grp*W+1 .. grp*W+W; then wave-uniform ldexp rescale
#define STEPS(buf, grp)                                                        \
  {                                                                            \
    int sb_ = (grp) * W + 1;                                                   \
    _Pragma("unroll")                                                          \
    for (int j_ = 0; j_ < W; ++j_) {                                           \
      int s_ = sb_ + j_;                                                       \
      if (s_ <= smax) {                                                        \
        double fx_ = (double)buf[j_].x, fy_ = (double)buf[j_].y;               \
        double fz_ = (double)buf[j_].z, fw_ = (double)buf[j_].w;               \
        double shrB_ = wave_shr1_f64(Bc);                                      \
        double na_ = fma(A, fx_, shrB_ * fz_);                                 \
        double nb_ = fma(Bc, fy_, A * fw_);                                    \
        A = na_; Bc = nb_;                                                     \
      }                                                                        \
    }                                                                          \
    int s2_ = (grp) * W + W; if (s2_ > smax) s2_ = smax;                       \
    int ulo_ = s2_ - (Tb - 1); if (ulo_ < 0) ulo_ = 0;                         \
    int uhi_ = s2_ < Ub ? s2_ : Ub;                                            \
    int um_ = (ulo_ + uhi_) >> 1;                                              \
    double ref_ = (um_ & 1) ? __shfl(Bc, um_ >> 1, 64)                         \
                            : __shfl(A, um_ >> 1, 64);                         \
    if (ref_ != 0.0) {                                                         \
      int e_ = ((__double2hiint(ref_) >> 20) & 0x7ff) - 1023;                  \
      A = ldexp(A, -e_); Bc = ldexp(Bc, -e_); scale += e_;                     \
    }                                                                          \
  }

  const int NW = (smax + W - 1) / W;       // windows covering steps 1..smax
  WAITW(0); LOADG(ba, 0);
  if (NW > 1) { WAITW(1); LOADG(bb, 1); }
  for (int k = 0; k < NW; k += 3) {
    if (k + 2 < NW) { WAITW(k + 2); LOADG(bc, k + 2); }
    STEPS(ba, k);
    if (k + 1 < NW) {
      if (k + 3 < NW) { WAITW(k + 3); LOADG(ba, k + 3); }
      STEPS(bb, k + 1);
      if (k + 2 < NW) {
        if (k + 4 < NW) { WAITW(k + 4); LOADG(bb, k + 4); }
        STEPS(bc, k + 2);
      }
    }
  }

  // answer cell (Tb-1, Ub) was produced at step smax (the final step)
  const int ansLane = Ub >> 1;
  double va = __shfl(A, ansLane, 64);
  double vb = __shfl(Bc, ansLane, 64);
  double v = (Ub & 1) ? vb : va;
  int ev = ((__double2hiint(v) >> 20) & 0x7ff) - 1023;
  double m = ldexp(v, -ev);
  float lg2 = (float)ev + flog2((float)m) + (float)scale;

  if (lane == 0) {
    __hip_atomic_store(&g_ps[b], lg2, __ATOMIC_RELEASE, __HIP_MEMORY_SCOPE_AGENT);
    int old = __hip_atomic_fetch_add(&g_ctr, 1, __ATOMIC_ACQ_REL,
                                     __HIP_MEMORY_SCOPE_AGENT);
    if (old == B - 1) {                    // all DP blocks done: no one spins
      float s = 0.0f;
      for (int i = 0; i < B; ++i)
        s += __hip_atomic_load(&g_ps[i], __ATOMIC_ACQUIRE, __HIP_MEMORY_SCOPE_AGENT);
      out[0] = -s * (LN2 / B);
      for (int i = 0; i < B; ++i)          // reset flags for next launch
        for (int w = 0; w < NWIN; ++w)
          __hip_atomic_store(&g_done[i][w], 0, __ATOMIC_RELAXED,
                             __HIP_MEMORY_SCOPE_AGENT);
      __hip_atomic_store(&g_ctr, 0, __ATOMIC_RELAXED, __HIP_MEMORY_SCOPE_AGENT);
    }
  }
#undef WAITW
#undef LOADG
#undef STEPS
}

extern "C" void kernel_launch(void* const* d_in, const int* in_sizes, int n_in,
                              void* d_out, int out_size, void* d_ws, size_t ws_size,
                              hipStream_t stream) {
  const float* logits = (const float*)d_in[0];
  const int* labels = (const int*)d_in[1];
  const int* logit_len = (const int*)d_in[2];
  const int* label_len = (const int*)d_in[3];
  float* out = (float*)d_out;

  hipLaunchKernelGGL(rnnt_fused, dim3(B + DIAGS), dim3(256), 0, stream,
                     logits, labels, logit_len, label_len, out);
}

// Round 9
// 56.036 us; speedup vs baseline: 1.5689x; 1.5689x over previous
//
#include <hip/hip_runtime.h>

// RNNT (Transducer) alpha-recursion loss, forward, mean reduction.
// B=4, T=512, U=100 (U+1=101 cols), V=1024, fp32.
//
// Linear-domain DP (recurrence is linear over (+,x)):
//   a[t][u] = a[t-1][u]*fB + a[t][u-1]*fE,  f* = exp2(log2e*logit)
// f64 state (answer ~ -700 log2; f32 overflowed in R6), wave-uniform ldexp
// rescale every 32 steps. R9 vs R7: the DP is ONE wave -> total ISSUE cycles
// are the wall; the 4 v_cvt_f64_f32 per step (~40% of issue) are moved into
// the wide gather (2400 idle waves there), which now stores f64 factor pairs:
//   g_P1[r][l] = {x=fB(u0), z=fE(u0-1)}   (A-update operands)
//   g_P2[r][l] = {y=fB(u1), w=fE(u0)}     (B-update operands)
// DP per step: 2x b128 load + 2 DPP + 2 v_mul_f64 + 2 v_fma_f64 (~24cy issue
// vs ~40). W=8-row load groups, modulo-3 software pipeline (192 buffer VGPRs,
// single wave so occupancy is irrelevant).
//
//  1) gather_kernel (wide, 612x4 blocks): rect-masked scatter-gather of
//     blank (v=0) / emit (v=label) from the 847MB logits, exp2 -> f64 pairs.
//  2) dp_kernel (4 blocks x 1 wave): lane l owns columns u=2l,2l+1; left
//     neighbor via DPP wave_shr:1 on both 32b halves of the double.
//     Answer produced at step smax, extracted post-loop as
//     exponent + log2(mantissa) + accumulated scale.

constexpr int B = 4, T = 512, U = 100, Up1 = 101, V = 1024;
constexpr int DIAGS = T + U;       // 612
constexpr int W = 8;               // DP steps / rows per load group
constexpr float LOG2E = 1.44269504088896340736f;
constexpr float LN2 = 0.69314718055994530942f;

__device__ double2 g_P1[(size_t)B * DIAGS * 64];   // {x, z}
__device__ double2 g_P2[(size_t)B * DIAGS * 64];   // {y, w}
__device__ float g_ps[B];          // per-sample log2(alpha_final)
__device__ int g_ctr = 0;

__device__ __forceinline__ int clampi(int x, int lo, int hi) {
  return x < lo ? lo : (x > hi ? hi : x);
}
__device__ __forceinline__ float fexp2(float x) {
  float r; asm("v_exp_f32 %0, %1" : "=v"(r) : "v"(x)); return r;
}
__device__ __forceinline__ float flog2(float x) {
  float r; asm("v_log_f32 %0, %1" : "=v"(r) : "v"(x)); return r;
}
// whole-wave shift by 1 on a double: lane l receives lane l-1's value
// (lane 0 keeps its own; its left factor is 0 so it never contributes)
__device__ __forceinline__ double wave_shr1_f64(double x) {
  int hi = __double2hiint(x), lo = __double2loint(x);
  hi = __builtin_amdgcn_update_dpp(hi, hi, 0x138 /*WF_SR1*/, 0xF, 0xF, false);
  lo = __builtin_amdgcn_update_dpp(lo, lo, 0x138 /*WF_SR1*/, 0xF, 0xF, false);
  return __hiloint2double(hi, lo);
}

__global__ __launch_bounds__(256) void gather_kernel(const float* __restrict__ logits,
                                                     const int* __restrict__ labels,
                                                     const int* __restrict__ logit_len,
                                                     const int* __restrict__ label_len) {
  const int b = blockIdx.y;
  const int r = blockIdx.x * 4 + (threadIdx.x >> 6);   // anti-diagonal row
  const int l = threadIdx.x & 63;                      // DP lane slot
  const int Tb = clampi(logit_len[b], 1, T);
  const int Ub = clampi(label_len[b], 1, U);
  if (r > Tb - 1 + Ub) return;                         // beyond answer diagonal

  const float* lg = logits + (size_t)b * T * Up1 * V;
  const int u0 = 2 * l, u1 = u0 + 1;
  float x = 0.0f, y = 0.0f, z = 0.0f, w = 0.0f;        // 0 == linear -inf

  int tx = r - u0;                                     // blank[tx][u0]
  if (u0 <= Ub && tx >= 0 && tx <= Tb - 1)
    x = fexp2(LOG2E * lg[((size_t)tx * Up1 + u0) * V]);
  int ty = r - u1;                                     // blank[ty][u1]
  if (u1 <= Ub && ty >= 0 && ty <= Tb - 1)
    y = fexp2(LOG2E * lg[((size_t)ty * Up1 + u1) * V]);
  int tz = r - u0 + 1;                                 // emit[tz][u0-1]
  if (u0 >= 1 && u0 <= Ub && tz >= 0 && tz <= Tb - 1) {
    int lab = clampi(labels[b * U + (u0 - 1)], 0, V - 1);
    z = fexp2(LOG2E * lg[((size_t)tz * Up1 + (u0 - 1)) * V + lab]);
  }
  int tw = r - u0;                                     // emit[tw][u0]
  if (u0 <= Ub - 1 && tw >= 0 && tw <= Tb - 1) {
    int lab = clampi(labels[b * U + u0], 0, V - 1);
    w = fexp2(LOG2E * lg[((size_t)tw * Up1 + u0) * V + lab]);
  }
  const size_t idx = ((size_t)b * DIAGS + r) * 64 + l;
  g_P1[idx] = make_double2((double)x, (double)z);
  g_P2[idx] = make_double2((double)y, (double)w);
}

__global__ __launch_bounds__(64, 1)
void dp_kernel(const int* __restrict__ logit_len,
               const int* __restrict__ label_len,
               float* __restrict__ out) {
  const int b = blockIdx.x;
  const int lane = threadIdx.x;
  const int Tb = clampi(logit_len[b], 1, T);
  const int Ub = clampi(label_len[b], 1, U);
  const int smax = Tb - 1 + Ub;        // diagonal (= step) of the answer cell
  const double2* P1 = g_P1 + (size_t)b * DIAGS * 64;
  const double2* P2 = g_P2 + (size_t)b * DIAGS * 64;

  // linear-domain f64 state: A = alpha[.][2*lane], Bc = alpha[.][2*lane+1]
  double A = (lane == 0) ? 1.0 : 0.0;  // alpha[0][0] = 1 (diag 0 done)
  double Bc = 0.0;
  int scale = 0;                       // accumulated log2 rescale

  double2 a1[W], a2[W], b1[W], b2[W], c1[W], c2[W];

  // group g holds rows g*W .. g*W+W-1 (step s consumes row s-1)
#define LOADG(u, v, grp)                                                       \
  {                                                                            \
    int base_ = (grp) * W;                                                     \
    _Pragma("unroll")                                                          \
    for (int j_ = 0; j_ < W; ++j_) {                                           \
      int r_ = base_ + j_; if (r_ > DIAGS - 1) r_ = DIAGS - 1;                 \
      u[j_] = P1[(size_t)r_ * 64 + lane];                                      \
      v[j_] = P2[(size_t)r_ * 64 + lane];                                      \
    }                                                                          \
  }

  // window grp = steps grp*W+1 .. grp*W+W; ldexp rescale every 4th window
#define STEPS(u, v, grp)                                                       \
  {                                                                            \
    int sb_ = (grp) * W + 1;                                                   \
    _Pragma("unroll")                                                          \
    for (int j_ = 0; j_ < W; ++j_) {                                           \
      int s_ = sb_ + j_;                                                       \
      if (s_ <= smax) {                                                        \
        double shrB_ = wave_shr1_f64(Bc);                                      \
        double na_ = fma(A, u[j_].x, shrB_ * u[j_].y);                         \
        double nb_ = fma(Bc, v[j_].x, A * v[j_].y);                            \
        A = na_; Bc = nb_;                                                     \
      }                                                                        \
    }                                                                          \
    if (((grp) & 3) == 3) {                                                    \
      int s2_ = (grp) * W + W; if (s2_ > smax) s2_ = smax;                     \
      int ulo_ = s2_ - (Tb - 1); if (ulo_ < 0) ulo_ = 0;                       \
      int uhi_ = s2_ < Ub ? s2_ : Ub;                                          \
      int um_ = (ulo_ + uhi_) >> 1;                                            \
      double ref_ = (um_ & 1) ? __shfl(Bc, um_ >> 1, 64)                       \
                              : __shfl(A, um_ >> 1, 64);                       \
      if (ref_ != 0.0) {                                                       \
        int e_ = ((__double2hiint(ref_) >> 20) & 0x7ff) - 1023;                \
        A = ldexp(A, -e_); Bc = ldexp(Bc, -e_); scale += e_;                   \
      }                                                                        \
    }                                                                          \
  }

  const int NW = (smax + W - 1) / W;   // windows covering steps 1..smax
  LOADG(a1, a2, 0);
  if (NW > 1) LOADG(b1, b2, 1);
  for (int k = 0; k < NW; k += 3) {
    if (k + 2 < NW) LOADG(c1, c2, k + 2);
    STEPS(a1, a2, k);
    if (k + 1 < NW) {
      if (k + 3 < NW) LOADG(a1, a2, k + 3);
      STEPS(b1, b2, k + 1);
      if (k + 2 < NW) {
        if (k + 4 < NW) LOADG(b1, b2, k + 4);
        STEPS(c1, c2, k + 2);
      }
    }
  }

  // answer cell (Tb-1, Ub) was produced at step smax (the final step)
  const int ansLane = Ub >> 1;
  double va = __shfl(A, ansLane, 64);
  double vb = __shfl(Bc, ansLane, 64);
  double v = (Ub & 1) ? vb : va;
  int ev = ((__double2hiint(v) >> 20) & 0x7ff) - 1023;
  double m = ldexp(v, -ev);
  float lg2 = (float)ev + flog2((float)m) + (float)scale;

  if (lane == 0) {
    __hip_atomic_store(&g_ps[b], lg2, __ATOMIC_RELEASE, __HIP_MEMORY_SCOPE_AGENT);
    int old = __hip_atomic_fetch_add(&g_ctr, 1, __ATOMIC_ACQ_REL,
                                     __HIP_MEMORY_SCOPE_AGENT);
    if (old == B - 1) {
      float s = 0.0f;
      for (int i = 0; i < B; ++i)
        s += __hip_atomic_load(&g_ps[i], __ATOMIC_ACQUIRE, __HIP_MEMORY_SCOPE_AGENT);
      out[0] = -s * (LN2 / B);
      __hip_atomic_store(&g_ctr, 0, __ATOMIC_RELAXED, __HIP_MEMORY_SCOPE_AGENT);
    }
  }
#undef LOADG
#undef STEPS
}

extern "C" void kernel_launch(void* const* d_in, const int* in_sizes, int n_in,
                              void* d_out, int out_size, void* d_ws, size_t ws_size,
                              hipStream_t stream) {
  const float* logits = (const float*)d_in[0];
  const int* labels = (const int*)d_in[1];
  const int* logit_len = (const int*)d_in[2];
  const int* label_len = (const int*)d_in[3];
  float* out = (float*)d_out;

  hipLaunchKernelGGL(gather_kernel, dim3(DIAGS / 4, B), dim3(256), 0, stream,
                     logits, labels, logit_len, label_len);
  hipLaunchKernelGGL(dp_kernel, dim3(B), dim3(64), 0, stream,
                     logit_len, label_len, out);
}

// Round 10
// 47.696 us; speedup vs baseline: 1.8433x; 1.1749x over previous
//
#include <hip/hip_runtime.h>

// RNNT (Transducer) alpha-recursion loss, forward, mean reduction.
// B=4, T=512, U=100 (U+1=101 cols), V=1024, fp32.
//
// Linear-domain DP (recurrence linear over (+,x)):
//   a[t][u] = a[t-1][u]*fB + a[t][u-1]*fE
// R10 = R9's f64-pair staging (no f64 converts on the single DP wave; the
// wide gather does them with 2400 idle waves) + R7's deep lookahead
// (W=12 x mod-3 = 24 rows ~ 720cy, covers cross-XCD L2/L3 latency that
// R9's 16-row lookahead missed) + NO in-loop rescale: the gather normalizes
// each diagonal's factors by 2^-m_r (m_r = rounded mean log2-factor of the
// row, computed by a 64-lane shfl_xor reduce); residual magnitude is
// entropy (<= ~612 log2) + zero-mean spread << f64 range. DP adds
// sum(m_r) once after the loop.
//
//  1) gather_kernel (wide, 612x4 blocks): rect-masked scatter-gather of
//     blank (v=0) / emit (v=label), per-row mean-normalized, exp2 -> f64:
//       g_P1[r][l] = {fB(u0), fE(u0-1)}  (A-update), g_P2 = {fB(u1), fE(u0)}
//  2) dp_kernel (4 blocks x 1 wave): lane l owns columns u=2l,2l+1; left
//     neighbor via DPP wave_shr:1 on both 32b halves of the double.
//     Per step: 2x b128 + 2 DPP + 2 v_mul_f64 + 2 v_fma_f64 (~30cy issue).

constexpr int B = 4, T = 512, U = 100, Up1 = 101, V = 1024;
constexpr int DIAGS = T + U;       // 612
constexpr int W = 12;              // DP steps / rows per load group
constexpr float LOG2E = 1.44269504088896340736f;
constexpr float LN2 = 0.69314718055994530942f;

__device__ double2 g_P1[(size_t)B * DIAGS * 64];   // {x=fB(u0), z=fE(u0-1)}
__device__ double2 g_P2[(size_t)B * DIAGS * 64];   // {y=fB(u1), w=fE(u0)}
__device__ float g_m[(size_t)B * DIAGS];           // per-diagonal log2 scale
__device__ float g_ps[B];          // per-sample log2(alpha_final)
__device__ int g_ctr = 0;

__device__ __forceinline__ int clampi(int x, int lo, int hi) {
  return x < lo ? lo : (x > hi ? hi : x);
}
__device__ __forceinline__ float fexp2(float x) {
  float r; asm("v_exp_f32 %0, %1" : "=v"(r) : "v"(x)); return r;
}
__device__ __forceinline__ float flog2(float x) {
  float r; asm("v_log_f32 %0, %1" : "=v"(r) : "v"(x)); return r;
}
// whole-wave shift by 1 on a double: lane l receives lane l-1's value
// (lane 0 keeps its own; its left factor is 0 so it never contributes)
__device__ __forceinline__ double wave_shr1_f64(double x) {
  int hi = __double2hiint(x), lo = __double2loint(x);
  hi = __builtin_amdgcn_update_dpp(hi, hi, 0x138 /*WF_SR1*/, 0xF, 0xF, false);
  lo = __builtin_amdgcn_update_dpp(lo, lo, 0x138 /*WF_SR1*/, 0xF, 0xF, false);
  return __hiloint2double(hi, lo);
}

__global__ __launch_bounds__(256) void gather_kernel(const float* __restrict__ logits,
                                                     const int* __restrict__ labels,
                                                     const int* __restrict__ logit_len,
                                                     const int* __restrict__ label_len) {
  const int b = blockIdx.y;
  const int r = blockIdx.x * 4 + (threadIdx.x >> 6);   // anti-diagonal row
  const int l = threadIdx.x & 63;                      // DP lane slot
  const int Tb = clampi(logit_len[b], 1, T);
  const int Ub = clampi(label_len[b], 1, U);
  if (r > Tb - 1 + Ub) return;                         // beyond answer diagonal

  const float* lg = logits + (size_t)b * T * Up1 * V;
  const int u0 = 2 * l, u1 = u0 + 1;
  float vx = 0.f, vy = 0.f, vz = 0.f, vw = 0.f;        // log2-scaled logits
  bool bx = false, by = false, bz = false, bw = false;

  int tx = r - u0;                                     // blank[tx][u0]
  if (u0 <= Ub && tx >= 0 && tx <= Tb - 1) {
    vx = LOG2E * lg[((size_t)tx * Up1 + u0) * V]; bx = true;
  }
  int ty = r - u1;                                     // blank[ty][u1]
  if (u1 <= Ub && ty >= 0 && ty <= Tb - 1) {
    vy = LOG2E * lg[((size_t)ty * Up1 + u1) * V]; by = true;
  }
  int tz = r - u0 + 1;                                 // emit[tz][u0-1]
  if (u0 >= 1 && u0 <= Ub && tz >= 0 && tz <= Tb - 1) {
    int lab = clampi(labels[b * U + (u0 - 1)], 0, V - 1);
    vz = LOG2E * lg[((size_t)tz * Up1 + (u0 - 1)) * V + lab]; bz = true;
  }
  int tw = r - u0;                                     // emit[tw][u0]
  if (u0 <= Ub - 1 && tw >= 0 && tw <= Tb - 1) {
    int lab = clampi(labels[b * U + u0], 0, V - 1);
    vw = LOG2E * lg[((size_t)tw * Up1 + u0) * V + lab]; bw = true;
  }

  // per-diagonal mean log2-factor (all valid entries of this row)
  float s = (bx ? vx : 0.f) + (by ? vy : 0.f) + (bz ? vz : 0.f) + (bw ? vw : 0.f);
  float c = (float)((int)bx + (int)by + (int)bz + (int)bw);
  for (int off = 32; off; off >>= 1) {
    s += __shfl_xor(s, off, 64);
    c += __shfl_xor(c, off, 64);
  }
  float m = (c > 0.f) ? rintf(s / c) : 0.f;            // wave-uniform integer

  const size_t idx = ((size_t)b * DIAGS + r) * 64 + l;
  g_P1[idx] = make_double2(bx ? (double)fexp2(vx - m) : 0.0,
                           bz ? (double)fexp2(vz - m) : 0.0);
  g_P2[idx] = make_double2(by ? (double)fexp2(vy - m) : 0.0,
                           bw ? (double)fexp2(vw - m) : 0.0);
  if (l == 0) g_m[(size_t)b * DIAGS + r] = m;
}

__global__ __launch_bounds__(64, 1)
void dp_kernel(const int* __restrict__ logit_len,
               const int* __restrict__ label_len,
               float* __restrict__ out) {
  const int b = blockIdx.x;
  const int lane = threadIdx.x;
  const int Tb = clampi(logit_len[b], 1, T);
  const int Ub = clampi(label_len[b], 1, U);
  const int smax = Tb - 1 + Ub;        // diagonal (= step) of the answer cell
  const double2* P1 = g_P1 + (size_t)b * DIAGS * 64;
  const double2* P2 = g_P2 + (size_t)b * DIAGS * 64;

  // linear-domain f64 state: A = alpha[.][2*lane], Bc = alpha[.][2*lane+1]
  double A = (lane == 0) ? 1.0 : 0.0;  // alpha[0][0] = 1 (diag 0 done)
  double Bc = 0.0;

  double2 a1[W], a2[W], b1[W], b2[W], c1[W], c2[W];

  // group g holds rows g*W .. g*W+W-1 (step s consumes row s-1)
#define LOADG(u, v, grp)                                                       \
  {                                                                            \
    int base_ = (grp) * W;                                                     \
    _Pragma("unroll")                                                          \
    for (int j_ = 0; j_ < W; ++j_) {                                           \
      int r_ = base_ + j_; if (r_ > DIAGS - 1) r_ = DIAGS - 1;                 \
      u[j_] = P1[(size_t)r_ * 64 + lane];                                      \
      v[j_] = P2[(size_t)r_ * 64 + lane];                                      \
    }                                                                          \
  }

  // window grp = steps grp*W+1 .. grp*W+W (no in-loop rescale: factors are
  // per-diagonal normalized; residual fits f64's 2^+-1023 comfortably)
#define STEPS(u, v, grp)                                                       \
  {                                                                            \
    int sb_ = (grp) * W + 1;                                                   \
    _Pragma("unroll")                                                          \
    for (int j_ = 0; j_ < W; ++j_) {                                           \
      int s_ = sb_ + j_;                                                       \
      if (s_ <= smax) {                                                        \
        double shrB_ = wave_shr1_f64(Bc);                                      \
        double na_ = fma(A, u[j_].x, shrB_ * u[j_].y);                         \
        double nb_ = fma(Bc, v[j_].x, A * v[j_].y);                            \
        A = na_; Bc = nb_;                                                     \
      }                                                                        \
    }                                                                          \
  }

  const int NW = (smax + W - 1) / W;   // windows covering steps 1..smax
  LOADG(a1, a2, 0);
  if (NW > 1) LOADG(b1, b2, 1);
  for (int k = 0; k < NW; k += 3) {
    if (k + 2 < NW) LOADG(c1, c2, k + 2);
    STEPS(a1, a2, k);
    if (k + 1 < NW) {
      if (k + 3 < NW) LOADG(a1, a2, k + 3);
      STEPS(b1, b2, k + 1);
      if (k + 2 < NW) {
        if (k + 4 < NW) LOADG(b1, b2, k + 4);
        STEPS(c1, c2, k + 2);
      }
    }
  }

  // answer cell (Tb-1, Ub) was produced at step smax (the final step)
  const int ansLane = Ub >> 1;
  double va = __shfl(A, ansLane, 64);
  double vb = __shfl(Bc, ansLane, 64);
  double v = (Ub & 1) ? vb : va;
  int ev = ((__double2hiint(v) >> 20) & 0x7ff) - 1023;
  double mant = ldexp(v, -ev);

  // accumulated per-diagonal scales: steps 1..smax consumed rows 0..smax-1
  float msum = 0.f;
  for (int r = lane; r <= smax - 1; r += 64)
    msum += g_m[(size_t)b * DIAGS + r];
  for (int off = 32; off; off >>= 1) msum += __shfl_xor(msum, off, 64);

  float lg2 = (float)ev + flog2((float)mant) + msum;

  if (lane == 0) {
    __hip_atomic_store(&g_ps[b], lg2, __ATOMIC_RELEASE, __HIP_MEMORY_SCOPE_AGENT);
    int old = __hip_atomic_fetch_add(&g_ctr, 1, __ATOMIC_ACQ_REL,
                                     __HIP_MEMORY_SCOPE_AGENT);
    if (old == B - 1) {
      float s = 0.0f;
      for (int i = 0; i < B; ++i)
        s += __hip_atomic_load(&g_ps[i], __ATOMIC_ACQUIRE, __HIP_MEMORY_SCOPE_AGENT);
      out[0] = -s * (LN2 / B);
      __hip_atomic_store(&g_ctr, 0, __ATOMIC_RELAXED, __HIP_MEMORY_SCOPE_AGENT);
    }
  }
#undef LOADG
#undef STEPS
}

extern "C" void kernel_launch(void* const* d_in, const int* in_sizes, int n_in,
                              void* d_out, int out_size, void* d_ws, size_t ws_size,
                              hipStream_t stream) {
  const float* logits = (const float*)d_in[0];
  const int* labels = (const int*)d_in[1];
  const int* logit_len = (const int*)d_in[2];
  const int* label_len = (const int*)d_in[3];
  float* out = (float*)d_out;

  hipLaunchKernelGGL(gather_kernel, dim3(DIAGS / 4, B), dim3(256), 0, stream,
                     logits, labels, logit_len, label_len);
  hipLaunchKernelGGL(dp_kernel, dim3(B), dim3(64), 0, stream,
                     logit_len, label_len, out);
}